// Round 1
// baseline (251.485 us; speedup 1.0000x reference)
//
#include <hip/hip_runtime.h>

#define CDIM 512
#define CKDIM 256
#define BDIM 4
#define HDIM 64
#define WDIM 64
#define NDIM 4096

// ws float offsets
#define OFF_XMH   0          // B*C*W = 131072
#define OFF_ROW   131072     // 131072
#define OFF_G     262144     // C*C = 262144
#define OFF_M     524288     // 131072
#define OFF_VM    655360     // 131072
#define OFF_GK    786432     // 512
#define OFF_GB    786944     // 512
#define OFF_SBB   787456     // 1 (padded)
#define OFF_CBQ   787712     // 256
#define OFF_E     788480     // B*N*W = 1048576  (end: 1,837,056 floats ~ 7.0 MB)

// xmh[b,c,w] = mean over h of x[b,c,h,w]
__global__ __launch_bounds__(256) void k_xmh(const float* __restrict__ x,
                                             float* __restrict__ xmh) {
  int t = threadIdx.x;
  int bc = blockIdx.x * 4 + (t >> 6);      // grid 512 -> covers B*C = 2048
  int w4 = t & 15;
  int hoff = (t >> 4) & 3;
  const float4* xp = (const float4*)(x) + (size_t)bc * (HDIM * 16);
  float4 acc = make_float4(0.f, 0.f, 0.f, 0.f);
#pragma unroll
  for (int k = 0; k < 16; ++k) {
    float4 v = xp[(hoff + 4 * k) * 16 + w4];
    acc.x += v.x; acc.y += v.y; acc.z += v.z; acc.w += v.w;
  }
  acc.x += __shfl_xor(acc.x, 16); acc.y += __shfl_xor(acc.y, 16);
  acc.z += __shfl_xor(acc.z, 16); acc.w += __shfl_xor(acc.w, 16);
  acc.x += __shfl_xor(acc.x, 32); acc.y += __shfl_xor(acc.y, 32);
  acc.z += __shfl_xor(acc.z, 32); acc.w += __shfl_xor(acc.w, 32);
  if (hoff == 0) {
    const float inv = 1.f / 64.f;
    float4 o = make_float4(acc.x * inv, acc.y * inv, acc.z * inv, acc.w * inv);
    ((float4*)xmh)[bc * 16 + w4] = o;
  }
}

// gk[c] = sum_o Wq[o,c]*bk[o] ; gb[c] = sum_o bq[o]*Wk[o,c] ; sbb = bq.bk
__global__ __launch_bounds__(256) void k_bias(const float* __restrict__ Wq,
                                              const float* __restrict__ bk,
                                              const float* __restrict__ bq,
                                              const float* __restrict__ Wk,
                                              float* __restrict__ gk,
                                              float* __restrict__ gb,
                                              float* __restrict__ sbb) {
  int c = blockIdx.x * 256 + threadIdx.x;
  float a = 0.f, b2 = 0.f;
  for (int o = 0; o < CKDIM; ++o) {
    a  += Wq[o * CDIM + c] * bk[o];
    b2 += bq[o] * Wk[o * CDIM + c];
  }
  gk[c] = a; gb[c] = b2;
  if (blockIdx.x == 0 && threadIdx.x == 0) {
    float s = 0.f;
    for (int o = 0; o < CKDIM; ++o) s += bq[o] * bk[o];
    sbb[0] = s;
  }
}

// row[b,c,w]: x1d (4-w mean of xmh + pe) then linear interp WP->W
__global__ __launch_bounds__(256) void k_row(const float* __restrict__ xmh,
                                             const float* __restrict__ pe_table,
                                             const int* __restrict__ pos,
                                             float* __restrict__ row) {
  int t = blockIdx.x * 256 + threadIdx.x;  // grid 512 -> 131072
  int w = t & 63, c = (t >> 6) & 511, b = t >> 15;
  float src = w * (15.0f / 63.0f);
  int i0 = (int)src;
  float tf = src - (float)i0;
  int i1 = i0 + 1; if (i1 > 15) i1 = 15;
  const float* xr = xmh + ((b << 9) + c) * 64;
  int ps0 = pos[b * (HDIM * WDIM) + 4 * i0] >> 3;
  int ps1 = pos[b * (HDIM * WDIM) + 4 * i1] >> 3;
  float s0 = xr[4 * i0] + xr[4 * i0 + 1] + xr[4 * i0 + 2] + xr[4 * i0 + 3];
  float s1 = xr[4 * i1] + xr[4 * i1 + 1] + xr[4 * i1 + 2] + xr[4 * i1 + 3];
  float v0 = 0.25f * s0 + pe_table[ps0 * CDIM + c];
  float v1 = 0.25f * s1 + pe_table[ps1 * CDIM + c];
  row[((b << 9) + c) * 64 + w] = v0 * (1.0f - tf) + v1 * tf;
}

// G[c,c'] = sum_o Wq[o,c]*Wk[o,c']
__global__ __launch_bounds__(256) void k_G(const float* __restrict__ Wq,
                                           const float* __restrict__ Wk,
                                           float* __restrict__ G) {
  int cp = blockIdx.x * 256 + threadIdx.x;  // c'
  int c0 = blockIdx.y * 8;
  float acc[8] = {0.f, 0.f, 0.f, 0.f, 0.f, 0.f, 0.f, 0.f};
  for (int o = 0; o < CKDIM; ++o) {
    float wk = Wk[o * CDIM + cp];
#pragma unroll
    for (int j = 0; j < 8; ++j) acc[j] += Wq[o * CDIM + c0 + j] * wk;
  }
#pragma unroll
  for (int j = 0; j < 8; ++j) G[(c0 + j) * CDIM + cp] = acc[j];
}

// M[b,c,w] = gk[c] + sum_c' G[c,c']*row[b,c',w]
__global__ __launch_bounds__(256) void k_M(const float* __restrict__ G,
                                           const float* __restrict__ row,
                                           const float* __restrict__ gk,
                                           float* __restrict__ M) {
  int t = threadIdx.x;
  int b = blockIdx.x >> 7;
  int c = (blockIdx.x & 127) * 4 + (t >> 6);
  int w = t & 63;
  const float* Gr = G + c * CDIM;
  const float* rb = row + (b << 9) * 64 + w;
  float acc = gk[c];
#pragma unroll 8
  for (int cp = 0; cp < CDIM; ++cp) acc += Gr[cp] * rb[cp * 64];
  M[((b << 9) + c) * 64 + w] = acc;
}

// cbq[b,w] = sbb + sum_c gb[c]*row[b,c,w]
__global__ void k_cbq(const float* __restrict__ gb,
                      const float* __restrict__ sbb,
                      const float* __restrict__ row,
                      float* __restrict__ cbq) {
  int b = blockIdx.x, w = threadIdx.x;
  float acc = sbb[0];
  const float* rb = row + (b << 9) * 64 + w;
#pragma unroll 8
  for (int c = 0; c < CDIM; ++c) acc += gb[c] * rb[c * 64];
  cbq[b * 64 + w] = acc;
}

// vm[b,c,w] = bv[c] + sum_c' Wv[c,c']*xmh[b,c',w]
__global__ __launch_bounds__(256) void k_vm(const float* __restrict__ Wv,
                                            const float* __restrict__ xmh,
                                            const float* __restrict__ bv,
                                            float* __restrict__ vm) {
  int t = threadIdx.x;
  int b = blockIdx.x >> 7;
  int c = (blockIdx.x & 127) * 4 + (t >> 6);
  int w = t & 63;
  const float* Wr = Wv + c * CDIM;
  const float* xb = xmh + (b << 9) * 64 + w;
  float acc = bv[c];
#pragma unroll 8
  for (int cp = 0; cp < CDIM; ++cp) acc += Wr[cp] * xb[cp * 64];
  vm[((b << 9) + c) * 64 + w] = acc;
}

// e[b,n,w] = cbq[b,w] + sum_c x[b,c,n]*M[b,c,w]   (per-b GEMM: x^T (N x C) @ M (C x 64))
__global__ __launch_bounds__(256) void k_e(const float* __restrict__ x,
                                           const float* __restrict__ M,
                                           const float* __restrict__ cbq,
                                           float* __restrict__ e) {
  __shared__ float xs[32][68];   // [c][n], padded
  __shared__ float Ms[32][68];   // [c][w], padded
  int t = threadIdx.x;
  int b = blockIdx.x >> 6;
  int n0 = (blockIdx.x & 63) << 6;
  int tw = t & 15, tn = t >> 4;
  int lw = t & 63, lc = t >> 6;
  float acc[4][4] = {};
  for (int c0 = 0; c0 < CDIM; c0 += 32) {
#pragma unroll
    for (int i = 0; i < 8; ++i) {
      int cl = i * 4 + lc;
      xs[cl][lw] = x[((size_t)(b * CDIM + c0 + cl)) * NDIM + n0 + lw];
      Ms[cl][lw] = M[(b * CDIM + c0 + cl) * 64 + lw];
    }
    __syncthreads();
#pragma unroll 8
    for (int cc = 0; cc < 32; ++cc) {
      float a[4], m[4];
#pragma unroll
      for (int j = 0; j < 4; ++j) { a[j] = xs[cc][tn * 4 + j]; m[j] = Ms[cc][tw * 4 + j]; }
#pragma unroll
      for (int jn = 0; jn < 4; ++jn)
#pragma unroll
        for (int jw = 0; jw < 4; ++jw) acc[jn][jw] += a[jn] * m[jw];
    }
    __syncthreads();
  }
  float4 cb = ((const float4*)(cbq + b * 64))[tw];
#pragma unroll
  for (int jn = 0; jn < 4; ++jn) {
    int n = n0 + tn * 4 + jn;
    float4 o;
    o.x = acc[jn][0] + cb.x;
    o.y = acc[jn][1] + cb.y;
    o.z = acc[jn][2] + cb.z;
    o.w = acc[jn][3] + cb.w;
    ((float4*)(e + ((size_t)(b * NDIM + n)) * 64))[tw] = o;
  }
}

// softmax over w (64) per (b,n), then out[b,c,n] = gamma * sum_w vm[b,c,w]*p[b,n,w] + x[b,c,n]
__global__ __launch_bounds__(256) void k_pv(const float* __restrict__ x,
                                            const float* __restrict__ vm,
                                            const float* __restrict__ e,
                                            const float* __restrict__ gamma,
                                            float* __restrict__ out) {
  __shared__ float es[WDIM][68];    // [w][n] transposed, padded
  __shared__ float vs[WDIM][132];   // [w][c] transposed, padded
  int t = threadIdx.x;
  int bx = blockIdx.x;
  int b = bx >> 8;
  int cg = (bx >> 6) & 3;
  int n0 = (bx & 63) << 6;
  int lw = t & 63, lr = t >> 6;
#pragma unroll
  for (int i = 0; i < 16; ++i) {
    int nl = i * 4 + lr;
    es[lw][nl] = e[((size_t)(b * NDIM + n0 + nl)) * 64 + lw];
  }
#pragma unroll
  for (int i = 0; i < 32; ++i) {
    int cl = i * 4 + lr;
    vs[lw][cl] = vm[(b * CDIM + cg * 128 + cl) * 64 + lw];
  }
  __syncthreads();
  {
    int r = t >> 2, sub = t & 3;
    float m = -3.4e38f;
#pragma unroll
    for (int k = 0; k < 16; ++k) m = fmaxf(m, es[4 * k + sub][r]);
    m = fmaxf(m, __shfl_xor(m, 1));
    m = fmaxf(m, __shfl_xor(m, 2));
    float s = 0.f;
#pragma unroll
    for (int k = 0; k < 16; ++k) {
      int w = 4 * k + sub;
      float p = __expf(es[w][r] - m);
      es[w][r] = p;
      s += p;
    }
    s += __shfl_xor(s, 1);
    s += __shfl_xor(s, 2);
    float inv = 1.f / s;
#pragma unroll
    for (int k = 0; k < 16; ++k) es[4 * k + sub][r] *= inv;
  }
  __syncthreads();
  int tc = t >> 4, tn = t & 15;
  float acc[8][4];
#pragma unroll
  for (int jc = 0; jc < 8; ++jc)
#pragma unroll
    for (int jn = 0; jn < 4; ++jn) acc[jc][jn] = 0.f;
#pragma unroll 4
  for (int w = 0; w < 64; ++w) {
    float av[8], pv[4];
#pragma unroll
    for (int jc = 0; jc < 8; ++jc) av[jc] = vs[w][tc * 8 + jc];
#pragma unroll
    for (int jn = 0; jn < 4; ++jn) pv[jn] = es[w][tn * 4 + jn];
#pragma unroll
    for (int jc = 0; jc < 8; ++jc)
#pragma unroll
      for (int jn = 0; jn < 4; ++jn) acc[jc][jn] += av[jc] * pv[jn];
  }
  float g = gamma[0];
#pragma unroll
  for (int jc = 0; jc < 8; ++jc) {
    int c = cg * 128 + tc * 8 + jc;
    size_t base = ((size_t)(b * CDIM + c)) * NDIM + n0 + tn * 4;
    float4 xr = *(const float4*)(x + base);
    float4 o;
    o.x = g * acc[jc][0] + xr.x;
    o.y = g * acc[jc][1] + xr.y;
    o.z = g * acc[jc][2] + xr.z;
    o.w = g * acc[jc][3] + xr.w;
    *(float4*)(out + base) = o;
  }
}

extern "C" void kernel_launch(void* const* d_in, const int* in_sizes, int n_in,
                              void* d_out, int out_size, void* d_ws, size_t ws_size,
                              hipStream_t stream) {
  const float* x     = (const float*)d_in[0];
  const float* Wq    = (const float*)d_in[1];
  const float* bq    = (const float*)d_in[2];
  const float* Wk    = (const float*)d_in[3];
  const float* bk    = (const float*)d_in[4];
  const float* Wv    = (const float*)d_in[5];
  const float* bv    = (const float*)d_in[6];
  const float* gamma = (const float*)d_in[7];
  const float* pe    = (const float*)d_in[8];
  const int*   pos   = (const int*)d_in[9];
  float* out = (float*)d_out;
  float* ws  = (float*)d_ws;

  float* xmh = ws + OFF_XMH;
  float* row = ws + OFF_ROW;
  float* G   = ws + OFF_G;
  float* M   = ws + OFF_M;
  float* vm  = ws + OFF_VM;
  float* gk  = ws + OFF_GK;
  float* gb  = ws + OFF_GB;
  float* sbb = ws + OFF_SBB;
  float* cbq = ws + OFF_CBQ;
  float* e   = ws + OFF_E;

  hipLaunchKernelGGL(k_xmh, dim3(512), dim3(256), 0, stream, x, xmh);
  hipLaunchKernelGGL(k_bias, dim3(2), dim3(256), 0, stream, Wq, bk, bq, Wk, gk, gb, sbb);
  hipLaunchKernelGGL(k_row, dim3(512), dim3(256), 0, stream, xmh, pe, pos, row);
  hipLaunchKernelGGL(k_G, dim3(2, 64), dim3(256), 0, stream, Wq, Wk, G);
  hipLaunchKernelGGL(k_M, dim3(512), dim3(256), 0, stream, G, row, gk, M);
  hipLaunchKernelGGL(k_cbq, dim3(4), dim3(64), 0, stream, gb, sbb, row, cbq);
  hipLaunchKernelGGL(k_vm, dim3(512), dim3(256), 0, stream, Wv, xmh, bv, vm);
  hipLaunchKernelGGL(k_e, dim3(256), dim3(256), 0, stream, x, M, cbq, e);
  hipLaunchKernelGGL(k_pv, dim3(1024), dim3(256), 0, stream, x, vm, e, gamma, out);
}

// Round 2
// 169.096 us; speedup vs baseline: 1.4872x; 1.4872x over previous
//
#include <hip/hip_runtime.h>

#define CDIM 512
#define OKD  256
#define NDIM 4096
#define NT   32

// ws float offsets
#define OFF_XMH 0          // B*C*64 = 131072
#define OFF_X1  131072     // B*C*16 = 32768
#define OFF_K1  163840     // B*256*16 = 16384
#define OFF_M1  180224     // B*C*16 = 32768
#define OFF_CB1 212992     // 64
#define OFF_VM  213056     // B*C*64 = 131072

// ---------------------------------------------------------------------------
// K1: x -> xmh[b,c,64] (h-mean) and x1pe[b,c,16] (h-mean + 4w-mean + pe)
__global__ __launch_bounds__(256) void k_reduce(const float* __restrict__ x,
                                                const float* __restrict__ pe,
                                                const int* __restrict__ pos,
                                                float* __restrict__ xmh,
                                                float* __restrict__ x1pe) {
  int t = threadIdx.x;
  int bc = blockIdx.x * 4 + (t >> 6);   // B*C = 2048, grid 512
  int w4 = t & 15;
  int hoff = (t >> 4) & 3;
  const float4* xp = (const float4*)(x) + (size_t)bc * (64 * 16);
  float4 acc = make_float4(0.f, 0.f, 0.f, 0.f);
#pragma unroll
  for (int k = 0; k < 16; ++k) {
    float4 v = xp[(hoff + 4 * k) * 16 + w4];
    acc.x += v.x; acc.y += v.y; acc.z += v.z; acc.w += v.w;
  }
  acc.x += __shfl_xor(acc.x, 16); acc.y += __shfl_xor(acc.y, 16);
  acc.z += __shfl_xor(acc.z, 16); acc.w += __shfl_xor(acc.w, 16);
  acc.x += __shfl_xor(acc.x, 32); acc.y += __shfl_xor(acc.y, 32);
  acc.z += __shfl_xor(acc.z, 32); acc.w += __shfl_xor(acc.w, 32);
  if (hoff == 0) {
    const float inv = 1.f / 64.f;
    float4 o = make_float4(acc.x * inv, acc.y * inv, acc.z * inv, acc.w * inv);
    ((float4*)xmh)[bc * 16 + w4] = o;
    int b = bc >> 9;
    int c = bc & 511;
    int ps = pos[b * 4096 + 4 * w4] >> 3;          // pos[b,0,4*i] // 8
    float x1 = (o.x + o.y + o.z + o.w) * 0.25f + pe[ps * CDIM + c];
    x1pe[bc * 16 + w4] = x1;
  }
}

// ---------------------------------------------------------------------------
// K2: vm[b,c,w] = Wv@xmh + bv  (blocks 0..127)
//     K1[b,o,i] = Wk@x1pe + bk (blocks 128..191)
__global__ __launch_bounds__(256) void k_vmk1(const float* __restrict__ Wv,
                                              const float* __restrict__ bv,
                                              const float* __restrict__ Wk,
                                              const float* __restrict__ bk,
                                              const float* __restrict__ xmh,
                                              const float* __restrict__ x1pe,
                                              float* __restrict__ vm,
                                              float* __restrict__ K1) {
  __shared__ float xsh[64][68];
  int t = threadIdx.x;
  int blk = blockIdx.x;
  if (blk < 128) {
    int b = blk >> 5;
    int c0 = (blk & 31) * 16;
    int c = c0 + (t >> 4);
    int wq = t & 15;
    const float* Wr = Wv + c * CDIM;
    float a0 = 0.f, a1 = 0.f, a2 = 0.f, a3 = 0.f;
    int cpl = t >> 2, quad = t & 3;
    for (int cp0 = 0; cp0 < CDIM; cp0 += 64) {
      __syncthreads();
#pragma unroll
      for (int rr = 0; rr < 4; ++rr) {
        *(float4*)&xsh[cpl][quad * 16 + rr * 4] =
            *(const float4*)&xmh[((size_t)(b * CDIM + cp0 + cpl)) * 64 + quad * 16 + rr * 4];
      }
      __syncthreads();
#pragma unroll 8
      for (int cp = 0; cp < 64; ++cp) {
        float wv = Wr[cp0 + cp];
        float4 xv = *(const float4*)&xsh[cp][wq * 4];
        a0 += wv * xv.x; a1 += wv * xv.y; a2 += wv * xv.z; a3 += wv * xv.w;
      }
    }
    float bb = bv[c];
    float4 o = make_float4(a0 + bb, a1 + bb, a2 + bb, a3 + bb);
    *(float4*)&vm[((size_t)(b * CDIM + c)) * 64 + wq * 4] = o;
  } else {
    int idx = blk - 128;                 // 0..63
    int b = idx >> 4;
    int o = (idx & 15) * 16 + (t >> 4);
    int i = t & 15;
    const float* Wr = Wk + o * CDIM;
    const float* xb = x1pe + (b << 9) * 16 + i;
    float acc = bk[o];
#pragma unroll 8
    for (int c = 0; c < CDIM; ++c) acc += Wr[c] * xb[c * 16];
    K1[((b << 8) + o) * 16 + i] = acc;
  }
}

// ---------------------------------------------------------------------------
// K3: M1[b,c,i] = Wq^T @ K1 (blocks 0..127) ; cb1[b,i] = bq . K1 (block 128)
__global__ __launch_bounds__(256) void k_m1(const float* __restrict__ Wq,
                                            const float* __restrict__ bq,
                                            const float* __restrict__ K1,
                                            float* __restrict__ M1,
                                            float* __restrict__ cb1) {
  int t = threadIdx.x;
  int blk = blockIdx.x;
  if (blk < 128) {
    int b = blk >> 5;
    int c = (blk & 31) * 16 + (t >> 4);
    int i = t & 15;
    const float* Wc = Wq + c;
    const float* Kb = K1 + (b << 8) * 16 + i;
    float acc = 0.f;
#pragma unroll 8
    for (int o = 0; o < OKD; ++o) acc += Wc[o * CDIM] * Kb[o * 16];
    M1[((b << 9) + c) * 16 + i] = acc;
  } else if (t < 64) {
    int b = t >> 4, i = t & 15;
    const float* Kb = K1 + (b << 8) * 16 + i;
    float acc = 0.f;
    for (int o = 0; o < OKD; ++o) acc += bq[o] * Kb[o * 16];
    cb1[b * 16 + i] = acc;
  }
}

// ---------------------------------------------------------------------------
// K4: fused attention per (b, 32-row n-tile):
//   E1 = x_tile^T @ M1 + cb1  ->  e = lerp_w(E1)  ->  softmax_w  ->
//   out = gamma * (vm @ p^T) + x
__global__ __launch_bounds__(256) void k_attn(const float* __restrict__ x,
                                              const float* __restrict__ M1,
                                              const float* __restrict__ cb1,
                                              const float* __restrict__ vm,
                                              const float* __restrict__ gamma,
                                              float* __restrict__ out) {
  __shared__ float es[64][36];     // p[w][n]
  __shared__ float e1s[NT][17];    // E1[n][i]
  __shared__ float xs[32][36];     // x chunk [c][n]
  __shared__ float m1c[32][16];    // M1 chunk [c][i]
  __shared__ float vs[64][132];    // vm chunk [w][c] (128 c)

  int t = threadIdx.x;
  int b = blockIdx.x >> 7;
  int n0 = (blockIdx.x & 127) * NT;

  // ---- Phase A: E1[n][2i] per thread -------------------------------------
  int an = t & 31;
  int ig = t >> 5;                 // i = 2*ig, 2*ig+1
  float e0 = 0.f, e1v = 0.f;
  int scl = t >> 3, snq = t & 7;
  const size_t xbase = (size_t)(b * CDIM) * NDIM + n0;
  for (int c0 = 0; c0 < CDIM; c0 += 32) {
    __syncthreads();
    *(float4*)&xs[scl][snq * 4] =
        *(const float4*)&x[xbase + (size_t)(c0 + scl) * NDIM + snq * 4];
    if (t < 128) {
      int cl = t >> 2, iq = t & 3;
      *(float4*)&m1c[cl][iq * 4] =
          *(const float4*)&M1[((b * CDIM + c0 + cl) << 4) + iq * 4];
    }
    __syncthreads();
#pragma unroll
    for (int cl = 0; cl < 32; ++cl) {
      float xv = xs[cl][an];
      float2 mm = *(const float2*)&m1c[cl][2 * ig];
      e0  += xv * mm.x;
      e1v += xv * mm.y;
    }
  }
  __syncthreads();
  e1s[an][2 * ig]     = e0  + cb1[b * 16 + 2 * ig];
  e1s[an][2 * ig + 1] = e1v + cb1[b * 16 + 2 * ig + 1];
  __syncthreads();

  // ---- Phase B: interp to w=64 + softmax over w --------------------------
  {
    int sn = t >> 3;    // 0..31
    int wg = t & 7;     // 8 w's per thread
    float pv[8];
    float m = -3.4e38f;
#pragma unroll
    for (int j = 0; j < 8; ++j) {
      int w = wg * 8 + j;
      float src = (float)w * (15.0f / 63.0f);
      int i0 = (int)src;
      float tf = src - (float)i0;
      int i1 = i0 + 1; if (i1 > 15) i1 = 15;
      float ev = e1s[sn][i0] * (1.0f - tf) + e1s[sn][i1] * tf;
      pv[j] = ev;
      m = fmaxf(m, ev);
    }
    m = fmaxf(m, __shfl_xor(m, 1));
    m = fmaxf(m, __shfl_xor(m, 2));
    m = fmaxf(m, __shfl_xor(m, 4));
    float s = 0.f;
#pragma unroll
    for (int j = 0; j < 8; ++j) { pv[j] = __expf(pv[j] - m); s += pv[j]; }
    s += __shfl_xor(s, 1);
    s += __shfl_xor(s, 2);
    s += __shfl_xor(s, 4);
    float inv = 1.f / s;
#pragma unroll
    for (int j = 0; j < 8; ++j) es[wg * 8 + j][sn] = pv[j] * inv;
  }
  __syncthreads();

  // ---- Phase C: out = gamma * vm @ p^T + x -------------------------------
  int cg = t >> 3;     // 0..31 -> 4 c each
  int ng = t & 7;      // -> 4 n each
  float g = gamma[0];
  for (int cc0 = 0; cc0 < CDIM; cc0 += 128) {
    __syncthreads();
    {
      int cl = t >> 1, half = t & 1;
      const float* vr = vm + (size_t)(b * CDIM + cc0 + cl) * 64 + half * 32;
#pragma unroll
      for (int j = 0; j < 8; ++j) {
        float4 v = *(const float4*)&vr[j * 4];
        int w = half * 32 + j * 4;
        vs[w][cl] = v.x; vs[w + 1][cl] = v.y; vs[w + 2][cl] = v.z; vs[w + 3][cl] = v.w;
      }
    }
    __syncthreads();
    float acc[4][4] = {};
#pragma unroll 8
    for (int w = 0; w < 64; ++w) {
      float4 vv = *(const float4*)&vs[w][cg * 4];
      float4 pp = *(const float4*)&es[w][ng * 4];
      acc[0][0] += vv.x * pp.x; acc[0][1] += vv.x * pp.y; acc[0][2] += vv.x * pp.z; acc[0][3] += vv.x * pp.w;
      acc[1][0] += vv.y * pp.x; acc[1][1] += vv.y * pp.y; acc[1][2] += vv.y * pp.z; acc[1][3] += vv.y * pp.w;
      acc[2][0] += vv.z * pp.x; acc[2][1] += vv.z * pp.y; acc[2][2] += vv.z * pp.z; acc[2][3] += vv.z * pp.w;
      acc[3][0] += vv.w * pp.x; acc[3][1] += vv.w * pp.y; acc[3][2] += vv.w * pp.z; acc[3][3] += vv.w * pp.w;
    }
#pragma unroll
    for (int j = 0; j < 4; ++j) {
      int c = cc0 + cg * 4 + j;
      size_t base = (size_t)(b * CDIM + c) * NDIM + n0 + ng * 4;
      float4 xr = *(const float4*)&x[base];
      float4 o;
      o.x = g * acc[j][0] + xr.x;
      o.y = g * acc[j][1] + xr.y;
      o.z = g * acc[j][2] + xr.z;
      o.w = g * acc[j][3] + xr.w;
      *(float4*)&out[base] = o;
    }
  }
}

// ---------------------------------------------------------------------------
extern "C" void kernel_launch(void* const* d_in, const int* in_sizes, int n_in,
                              void* d_out, int out_size, void* d_ws, size_t ws_size,
                              hipStream_t stream) {
  const float* x     = (const float*)d_in[0];
  const float* Wq    = (const float*)d_in[1];
  const float* bq    = (const float*)d_in[2];
  const float* Wk    = (const float*)d_in[3];
  const float* bk    = (const float*)d_in[4];
  const float* Wv    = (const float*)d_in[5];
  const float* bv    = (const float*)d_in[6];
  const float* gamma = (const float*)d_in[7];
  const float* pe    = (const float*)d_in[8];
  const int*   pos   = (const int*)d_in[9];
  float* out = (float*)d_out;
  float* ws  = (float*)d_ws;

  float* xmh  = ws + OFF_XMH;
  float* x1pe = ws + OFF_X1;
  float* K1   = ws + OFF_K1;
  float* M1   = ws + OFF_M1;
  float* cb1  = ws + OFF_CB1;
  float* vm   = ws + OFF_VM;

  hipLaunchKernelGGL(k_reduce, dim3(512), dim3(256), 0, stream, x, pe, pos, xmh, x1pe);
  hipLaunchKernelGGL(k_vmk1, dim3(192), dim3(256), 0, stream, Wv, bv, Wk, bk, xmh, x1pe, vm, K1);
  hipLaunchKernelGGL(k_m1, dim3(129), dim3(256), 0, stream, Wq, bq, K1, M1, cb1);
  hipLaunchKernelGGL(k_attn, dim3(512), dim3(256), 0, stream, x, M1, cb1, vm, gamma, out);
}